// Round 10
// baseline (274.317 us; speedup 1.0000x reference)
//
#include <hip/hip_runtime.h>
#include <hip/hip_bf16.h>
#include <stdint.h>

typedef __bf16 bf16;
typedef __bf16 bf16x8 __attribute__((ext_vector_type(8)));
typedef float  f32x4 __attribute__((ext_vector_type(4)));

#define SEQ   4096
#define DIM_  1024
#define HD_   64
#define NEG_BIG (-30000.0f)   // finite mask sentinel: exp2(NEG_BIG*log2e - C) == 0

// load 8 contiguous fp32, round-to-nearest-even to bf16x8
__device__ __forceinline__ bf16x8 cvt8(const float* p) {
    f32x4 a = *(const f32x4*)p, b = *(const f32x4*)(p + 4);
    bf16x8 r;
    r[0]=(bf16)a[0]; r[1]=(bf16)a[1]; r[2]=(bf16)a[2]; r[3]=(bf16)a[3];
    r[4]=(bf16)b[0]; r[5]=(bf16)b[1]; r[6]=(bf16)b[2]; r[7]=(bf16)b[3];
    return r;
}

// ---------------------------------------------------------------------------
// Pre-pass: x -> x_bf (bf16), {qw,kw,vw} -> wcat_bf [1536][1024] bf16,
// {qb,kb,vb} -> bcat fp32 [1536]. One 8-elem chunk per thread.
// ---------------------------------------------------------------------------
__global__ __launch_bounds__(256)
void cvt_pre(const float* __restrict__ x,
             const float* __restrict__ qw, const float* __restrict__ kw,
             const float* __restrict__ vw,
             const float* __restrict__ qb, const float* __restrict__ kb,
             const float* __restrict__ vb,
             bf16* __restrict__ x_bf, bf16* __restrict__ wcat,
             float* __restrict__ bcat)
{
    const int NX = (SEQ * DIM_) / 8;          // 524288 chunks of x
    const int NW = (1536 * 1024) / 8;         // 196608 chunks of wcat
    int i = blockIdx.x * 256 + threadIdx.x;
    if (i < NX) {
        *(bf16x8*)(x_bf + (size_t)i * 8) = cvt8(x + (size_t)i * 8);
    } else if (i < NX + NW) {
        int e = (i - NX) * 8;
        const float* src;
        if (e < 1024 * 1024)      src = qw + e;
        else if (e < 1280 * 1024) src = kw + (e - 1024 * 1024);
        else                      src = vw + (e - 1280 * 1024);
        *(bf16x8*)(wcat + e) = cvt8(src);
    }
    if (i < 1536)
        bcat[i] = (i < 1024) ? qb[i] : (i < 1280) ? kb[i - 1024] : vb[i - 1280];
}

// ---------------------------------------------------------------------------
// GEMM: C = A @ B^T + bias. A bf16 [M][1024]. 128x128 tile, BK=32, 4 waves x
// (64x64), 4x4 accs — the R5/R8-proven shape.
// MODE 1 (QKV): B = wcat bf16 [1536][1024], bias = bcat. Epilogue scatters
//   Q -> Qbf (x0.125), K -> C1 fp32 + Kbf bf16, V -> C2 fp32 + VTbf bf16^T.
// MODE 0 (O-proj): B = ow fp32 (cvt8 staging, proven), bias fp32, C0 fp32.
// ---------------------------------------------------------------------------
template<int MODE>
__global__ __launch_bounds__(256)
void gemm_bt(const bf16* __restrict__ A, const void* __restrict__ Bw,
             const float* __restrict__ bias_all,
             float* __restrict__ C0, float* __restrict__ C1, float* __restrict__ C2,
             bf16* __restrict__ Qbf, bf16* __restrict__ Kbf, bf16* __restrict__ VTbf)
{
    const int K = 1024;
    const int tid  = threadIdx.x;
    const int lane = tid & 63, wave = tid >> 6;
    const int qd = lane >> 4, ln = lane & 15;
    const int wm = (wave & 1) * 64, wn = (wave >> 1) * 64;
    const int m0 = blockIdx.x * 128, n0 = blockIdx.y * 128;

    const bf16*  Bpb = (MODE == 1) ? (const bf16*)Bw + (size_t)n0 * K : nullptr;
    const float* Bpf = (MODE == 0) ? (const float*)Bw + (size_t)n0 * K : nullptr;
    const float* bias = bias_all + n0;

    __shared__ bf16 As[128*32];
    __shared__ bf16 Bs[128*32];

    f32x4 acc[4][4] = {};

    for (int k0 = 0; k0 < K; k0 += 32) {
        bf16x8 ra[2], rb[2];
        #pragma unroll
        for (int i = 0; i < 2; ++i) {
            int s   = i*256 + tid;             // 8-elem chunk id, 512 per matrix
            int row = s >> 2, ch = s & 3;
            ra[i] = *(const bf16x8*)(A + (size_t)(m0+row)*K + k0 + ch*8);
            if (MODE == 1)
                rb[i] = *(const bf16x8*)(Bpb + (size_t)row*K + k0 + ch*8);
            else
                rb[i] = cvt8(Bpf + (size_t)row*K + k0 + ch*8);
        }
        __syncthreads();                       // prev-iter LDS reads done
        #pragma unroll
        for (int i = 0; i < 2; ++i) {
            int s   = i*256 + tid;
            int row = s >> 2, ch = s & 3;
            *(bf16x8*)(As + row*32 + ch*8) = ra[i];
            *(bf16x8*)(Bs + row*32 + ch*8) = rb[i];
        }
        __syncthreads();                       // staging visible to all waves

        bf16x8 af[4], bg[4];
        #pragma unroll
        for (int i = 0; i < 4; ++i)
            af[i] = *(const bf16x8*)(As + (wm + i*16 + ln)*32 + qd*8);
        #pragma unroll
        for (int j = 0; j < 4; ++j)
            bg[j] = *(const bf16x8*)(Bs + (wn + j*16 + ln)*32 + qd*8);

        #pragma unroll
        for (int i = 0; i < 4; ++i)
            #pragma unroll
            for (int j = 0; j < 4; ++j)
                acc[i][j] = __builtin_amdgcn_mfma_f32_16x16x32_bf16(af[i], bg[j], acc[i][j], 0, 0, 0);
    }

    // epilogue: C/D layout row = quad*4+reg, col = lane&15 (proven)
    #pragma unroll
    for (int i = 0; i < 4; ++i) {
        #pragma unroll
        for (int j = 0; j < 4; ++j) {
            int colg = n0 + wn + j*16 + ln;
            float bv = bias[wn + j*16 + ln];
            #pragma unroll
            for (int r = 0; r < 4; ++r) {
                int rowg = m0 + wm + i*16 + qd*4 + r;
                float v = acc[i][j][r] + bv;
                if (MODE == 0) {
                    C0[(size_t)rowg*1024 + colg] = v;
                } else if (colg < 1024) {
                    Qbf[(size_t)rowg*1024 + colg] = (bf16)(v * 0.125f);
                } else if (colg < 1280) {
                    int c2 = colg - 1024;
                    size_t idx = (size_t)(c2 >> 6)*(SEQ*HD_) + (size_t)rowg*HD_ + (c2 & 63);
                    C1[idx]  = v;
                    Kbf[idx] = (bf16)v;
                } else {
                    int c2 = colg - 1280;
                    C2[(size_t)(c2 >> 6)*(SEQ*HD_) + (size_t)rowg*HD_ + (c2 & 63)] = v;
                    VTbf[(size_t)(c2 >> 6)*(HD_*SEQ) + (size_t)(c2 & 63)*SEQ + rowg] = (bf16)v;
                }
            }
        }
    }
}

// ---------------------------------------------------------------------------
// Flash attention, causal GQA, full MFMA (byte-identical to R9-proven).
// 64-row Q blocks, grid 1024 LPT-ordered; fixed-base softmax (m=16), l
// deferred to the epilogue. Q bf16 x0.125; K [4][T][64]; V^T [4][64][T].
// ---------------------------------------------------------------------------
__global__ __launch_bounds__(256)
void attn_fwd(const bf16* __restrict__ Q, const bf16* __restrict__ Kc,
              const bf16* __restrict__ VT, bf16* __restrict__ att)
{
    const int bid  = blockIdx.x;           // 0..1023
    const int head = bid & 15;
    const int mt   = 63 - (bid >> 4);      // descending work: LPT scheduling
    const int qb   = mt * 64;
    const int kvh  = head >> 2;

    const int tid = threadIdx.x, lane = tid & 63, wave = tid >> 6;
    const int qd = lane >> 4, ln = lane & 15;
    const int rw0 = qb + wave * 16;        // 16 Q rows per wave

    __shared__ bf16 Ks[64*72];             // [t][d], +8 pad (proven)
    __shared__ bf16 Vt[64*72];             // [d][t], +8 pad (proven)
    __shared__ bf16 Ps[4][16*72];          // per-wave P, +8 pad

    const bf16* Kbase = Kc + (size_t)kvh * SEQ * HD_;
    const bf16* Vbase = VT + (size_t)kvh * HD_ * SEQ;

    bf16x8 aq[2];
    #pragma unroll
    for (int ks = 0; ks < 2; ++ks)
        aq[ks] = *(const bf16x8*)(Q + (size_t)(rw0 + ln)*DIM_ + head*HD_ + ks*32 + qd*8);

    f32x4 o[4] = {};
    float l_p[4] = {0.f, 0.f, 0.f, 0.f};

    const float LOG2E = 1.4426950408889634f;
    const float C16   = 16.0f * LOG2E;
    const int nkt = mt + 1;

    for (int kt = 0; kt < nkt; ++kt) {
        const int kb = kt * 64;

        bf16x8 rk[2], rv[2];
        #pragma unroll
        for (int i = 0; i < 2; ++i) {
            int s = i*256 + tid;
            int r8 = s >> 3, ch = s & 7;
            rk[i] = *(const bf16x8*)(Kbase + (size_t)(kb + r8)*HD_ + ch*8);
            rv[i] = *(const bf16x8*)(Vbase + (size_t)r8*SEQ + kb + ch*8);
        }
        __syncthreads();
        #pragma unroll
        for (int i = 0; i < 2; ++i) {
            int s = i*256 + tid;
            int r8 = s >> 3, ch = s & 7;
            *(bf16x8*)(Ks + r8*72 + ch*8) = rk[i];
            *(bf16x8*)(Vt + r8*72 + ch*8) = rv[i];
        }
        __syncthreads();

        f32x4 S[4] = {};
        #pragma unroll
        for (int ks = 0; ks < 2; ++ks) {
            bf16x8 bk[4];
            #pragma unroll
            for (int nf = 0; nf < 4; ++nf)
                bk[nf] = *(const bf16x8*)(Ks + (nf*16 + ln)*72 + ks*32 + qd*8);
            #pragma unroll
            for (int nf = 0; nf < 4; ++nf)
                S[nf] = __builtin_amdgcn_mfma_f32_16x16x32_bf16(aq[ks], bk[nf], S[nf], 0, 0, 0);
        }

        if (kt == nkt - 1) {
            #pragma unroll
            for (int nf = 0; nf < 4; ++nf) {
                int col = kb + nf*16 + ln;
                #pragma unroll
                for (int r = 0; r < 4; ++r) {
                    int row = rw0 + qd*4 + r;
                    if (col > row) S[nf][r] = NEG_BIG;
                }
            }
        }

        bf16* Pw = &Ps[wave][0];
        #pragma unroll
        for (int r = 0; r < 4; ++r) {
            #pragma unroll
            for (int nf = 0; nf < 4; ++nf) {
                float p = exp2f(S[nf][r] * LOG2E - C16);
                l_p[r] += p;
                Pw[(qd*4 + r)*72 + nf*16 + ln] = (bf16)p;
            }
        }
        asm volatile("s_waitcnt lgkmcnt(0)" ::: "memory");

        #pragma unroll
        for (int ks = 0; ks < 2; ++ks) {
            bf16x8 bv[4];
            #pragma unroll
            for (int nf = 0; nf < 4; ++nf)
                bv[nf] = *(const bf16x8*)(Vt + (nf*16 + ln)*72 + ks*32 + qd*8);
            bf16x8 ap = *(const bf16x8*)(&Ps[wave][ln*72 + ks*32 + qd*8]);
            #pragma unroll
            for (int nf = 0; nf < 4; ++nf)
                o[nf] = __builtin_amdgcn_mfma_f32_16x16x32_bf16(ap, bv[nf], o[nf], 0, 0, 0);
        }
    }

    #pragma unroll
    for (int r = 0; r < 4; ++r) {
        float l = l_p[r];
        l += __shfl_xor(l, 1);
        l += __shfl_xor(l, 2);
        l += __shfl_xor(l, 4);
        l += __shfl_xor(l, 8);
        float inv = 1.0f / l;
        int trow = rw0 + qd*4 + r;
        #pragma unroll
        for (int nf = 0; nf < 4; ++nf)
            att[(size_t)trow*DIM_ + head*HD_ + nf*16 + ln] = (bf16)(o[nf][r] * inv);
    }
}

extern "C" void kernel_launch(void* const* d_in, const int* in_sizes, int n_in,
                              void* d_out, int out_size, void* d_ws, size_t ws_size,
                              hipStream_t stream)
{
    const float* x  = (const float*)d_in[0];
    // d_in[1] = causal mask (bool tril) -> not read
    const float* qw = (const float*)d_in[2];
    const float* qb = (const float*)d_in[3];
    const float* kw = (const float*)d_in[4];
    const float* kb = (const float*)d_in[5];
    const float* vw = (const float*)d_in[6];
    const float* vb = (const float*)d_in[7];
    const float* ow = (const float*)d_in[8];
    const float* ob = (const float*)d_in[9];

    float* out  = (float*)d_out;                       // [4096][1024] fp32 final
    float* kout = out  + (size_t)SEQ * DIM_;           // [4][4096][64] fp32 final
    float* vout = kout + (size_t)4 * SEQ * HD_;        // [4][4096][64] fp32 final

    // bf16 scratch inside the dead 16 MB out region (overwritten by O-proj):
    bf16*  q_bf  = (bf16*)d_out;                       // [4096][1024]  @ +0   (8 MB)
    bf16*  k_bf  = q_bf + (size_t)SEQ * DIM_;          // [4][4096][64] @ +8M  (2 MB)
    bf16*  vT_bf = k_bf + (size_t)4 * SEQ * HD_;       // [4][64][4096] @ +10M (2 MB)
    bf16*  wcat  = vT_bf + (size_t)4 * HD_ * SEQ;      // [1536][1024]  @ +12M (3 MB)
    float* bcat  = (float*)(wcat + (size_t)1536*1024); //               @ +15M (6 KB)
    // d_ws (8 MB): x_bf during QKV gemm, then att after attention
    // (stream-ordered: x_bf is dead before attn_fwd writes att).
    bf16* x_bf = (bf16*)d_ws;                          // [4096][1024] bf16
    bf16* att  = (bf16*)d_ws;                          // [4096][1024] bf16

    // pre-pass: bf16 conversions (x, qkv weights, biases)
    cvt_pre<<<dim3(2816), 256, 0, stream>>>(x, qw, kw, vw, qb, kb, vb,
                                            x_bf, wcat, bcat);
    // QKV projection: Q->q_bf, K->kout+k_bf, V->vout+vT_bf(transposed)
    gemm_bt<1><<<dim3(32, 12), 256, 0, stream>>>(x_bf, wcat, bcat,
                                                 nullptr, kout, vout,
                                                 q_bf, k_bf, vT_bf);
    // causal GQA flash attention (R9-proven)
    attn_fwd<<<dim3(1024), 256, 0, stream>>>(q_bf, k_bf, vT_bf, att);
    // output projection: att bf16 @ ow^T -> out fp32 (overwrites scratch)
    gemm_bt<0><<<dim3(32, 8), 256, 0, stream>>>(att, ow, ob,
                                                out, nullptr, nullptr,
                                                nullptr, nullptr, nullptr);
}

// Round 11
// 271.835 us; speedup vs baseline: 1.0091x; 1.0091x over previous
//
#include <hip/hip_runtime.h>
#include <hip/hip_bf16.h>
#include <stdint.h>

typedef __bf16 bf16;
typedef __bf16 bf16x8 __attribute__((ext_vector_type(8)));
typedef float  f32x4 __attribute__((ext_vector_type(4)));

#define SEQ   4096
#define DIM_  1024
#define HD_   64
#define NEG_BIG (-30000.0f)   // finite mask sentinel: exp2(NEG_BIG*log2e - C) == 0

// load 8 contiguous fp32, round-to-nearest-even to bf16x8
__device__ __forceinline__ bf16x8 cvt8(const float* p) {
    f32x4 a = *(const f32x4*)p, b = *(const f32x4*)(p + 4);
    bf16x8 r;
    r[0]=(bf16)a[0]; r[1]=(bf16)a[1]; r[2]=(bf16)a[2]; r[3]=(bf16)a[3];
    r[4]=(bf16)b[0]; r[5]=(bf16)b[1]; r[6]=(bf16)b[2]; r[7]=(bf16)b[3];
    return r;
}

// async global->LDS, 16 B per lane (m97 mechanism; LDS dest must be
// wave-uniform base + lane*16 — our slot layout satisfies this exactly)
__device__ __forceinline__ void async_cp16(const bf16* g, bf16* l) {
    __builtin_amdgcn_global_load_lds(
        (const __attribute__((address_space(1))) void*)g,
        (__attribute__((address_space(3))) void*)l, 16, 0, 0);
}

// ---------------------------------------------------------------------------
// Pre-pass: x -> x_bf (bf16), {qw,kw,vw} -> wcat [1536][1024] bf16,
// {qb,kb,vb} -> bcat fp32 [1536]. One 8-elem chunk per thread.
// ---------------------------------------------------------------------------
__global__ __launch_bounds__(256)
void cvt_pre(const float* __restrict__ x,
             const float* __restrict__ qw, const float* __restrict__ kw,
             const float* __restrict__ vw,
             const float* __restrict__ qb, const float* __restrict__ kb,
             const float* __restrict__ vb,
             bf16* __restrict__ x_bf, bf16* __restrict__ wcat,
             float* __restrict__ bcat)
{
    const int NX = (SEQ * DIM_) / 8;          // 524288 chunks of x
    const int NW = (1536 * 1024) / 8;         // 196608 chunks of wcat
    int i = blockIdx.x * 256 + threadIdx.x;
    if (i < NX) {
        *(bf16x8*)(x_bf + (size_t)i * 8) = cvt8(x + (size_t)i * 8);
    } else if (i < NX + NW) {
        int e = (i - NX) * 8;
        const float* src;
        if (e < 1024 * 1024)      src = qw + e;
        else if (e < 1280 * 1024) src = kw + (e - 1024 * 1024);
        else                      src = vw + (e - 1280 * 1024);
        *(bf16x8*)(wcat + e) = cvt8(src);
    }
    if (i < 1536)
        bcat[i] = (i < 1024) ? qb[i] : (i < 1280) ? kb[i - 1024] : vb[i - 1280];
}

// ---------------------------------------------------------------------------
// Post-QKV pass: derive attention's bf16 K/V from the fp32 finals.
//   k_bf [4][T][64]  = cvt(kout)            (coalesced copy)
//   vT_bf[4][64][T]  = cvt(vout) transposed (padded-LDS 64x64 tile transpose;
//   scalar b16 LDS writes = proven P-store mechanism family, both global
//   sides coalesced b128). Removes the 8KB-stride scatter from the gemm
//   epilogue (R8-R10's invariant ~60 us tail).
// ---------------------------------------------------------------------------
__global__ __launch_bounds__(256)
void kv_cvt(const float* __restrict__ kout, const float* __restrict__ vout,
            bf16* __restrict__ k_bf, bf16* __restrict__ vT_bf)
{
    const int b   = blockIdx.x;            // 0..255
    const int kvh = b >> 6, tb = b & 63;   // kv head, 64-row t-tile
    const int tid = threadIdx.x;

    __shared__ bf16 T[64*72];              // [d][t], +8 pad

    const float* Ksrc = kout + ((size_t)kvh*SEQ + tb*64) * HD_;
    const float* Vsrc = vout + ((size_t)kvh*SEQ + tb*64) * HD_;

    #pragma unroll
    for (int i = 0; i < 2; ++i) {
        int s = i*256 + tid;               // 512 chunks of 8 elements
        int r = s >> 3, c = s & 7;         // t-row in tile, d-chunk
        bf16x8 k8 = cvt8(Ksrc + (size_t)r*HD_ + c*8);
        *(bf16x8*)(k_bf + ((size_t)kvh*SEQ + tb*64 + r)*HD_ + c*8) = k8;
        bf16x8 v8 = cvt8(Vsrc + (size_t)r*HD_ + c*8);
        #pragma unroll
        for (int e = 0; e < 8; ++e)
            T[(c*8 + e)*72 + r] = v8[e];   // scalar transpose write
    }
    __syncthreads();
    #pragma unroll
    for (int i = 0; i < 2; ++i) {
        int s = i*256 + tid;
        int d = s >> 3, c = s & 7;
        *(bf16x8*)(vT_bf + ((size_t)kvh*HD_ + d)*SEQ + tb*64 + c*8) =
            *(const bf16x8*)(T + d*72 + c*8);
    }
}

// ---------------------------------------------------------------------------
// GEMM: C = A @ B^T + bias. A bf16 [M][1024]. 128x128 tile, BK=32, 4 waves x
// (64x64), 4x4 accs (R5/R8-proven shape) + global_load_lds width-16 staging
// (m97 lever) for all bf16 operands.
// MODE 1 (QKV): B = wcat bf16 (async), bias = bcat. Epilogue = R5-proven
//   scatter: Q -> Qbf (x0.125), K -> C1 fp32, V -> C2 fp32. No side copies.
// MODE 0 (O-proj): B = ow fp32 (cvt8 register staging, proven), C0 fp32.
// ---------------------------------------------------------------------------
template<int MODE>
__global__ __launch_bounds__(256)
void gemm_bt(const bf16* __restrict__ A, const void* __restrict__ Bw,
             const float* __restrict__ bias_all,
             float* __restrict__ C0, float* __restrict__ C1, float* __restrict__ C2,
             bf16* __restrict__ Qbf)
{
    const int K = 1024;
    const int tid  = threadIdx.x;
    const int lane = tid & 63, wave = tid >> 6;
    const int qd = lane >> 4, ln = lane & 15;
    const int wm = (wave & 1) * 64, wn = (wave >> 1) * 64;
    const int m0 = blockIdx.x * 128, n0 = blockIdx.y * 128;

    const bf16*  Bpb = (MODE == 1) ? (const bf16*)Bw + (size_t)n0 * K : nullptr;
    const float* Bpf = (MODE == 0) ? (const float*)Bw + (size_t)n0 * K : nullptr;
    const float* bias = bias_all + n0;

    __shared__ bf16 As[128*32];
    __shared__ bf16 Bs[128*32];

    f32x4 acc[4][4] = {};

    for (int k0 = 0; k0 < K; k0 += 32) {
        bf16x8 rb[2];
        if (MODE == 0) {                       // B fp32: prefetch + cvt to regs
            #pragma unroll
            for (int i = 0; i < 2; ++i) {
                int s = i*256 + tid;
                int row = s >> 2, ch = s & 3;
                rb[i] = cvt8(Bpf + (size_t)row*K + k0 + ch*8);
            }
        }
        __syncthreads();                       // prev-iter LDS reads done
        #pragma unroll
        for (int i = 0; i < 2; ++i) {
            int s   = i*256 + tid;             // 16B slot id, 512 per matrix
            int row = s >> 2, ch = s & 3;
            async_cp16(A + (size_t)(m0+row)*K + k0 + ch*8, As + s*8);
            if (MODE == 1)
                async_cp16(Bpb + (size_t)row*K + k0 + ch*8, Bs + s*8);
            else
                *(bf16x8*)(Bs + s*8) = rb[i];
        }
        __builtin_amdgcn_s_waitcnt(0);         // drain async (m97 structure)
        __syncthreads();

        bf16x8 af[4], bg[4];
        #pragma unroll
        for (int i = 0; i < 4; ++i)
            af[i] = *(const bf16x8*)(As + (wm + i*16 + ln)*32 + qd*8);
        #pragma unroll
        for (int j = 0; j < 4; ++j)
            bg[j] = *(const bf16x8*)(Bs + (wn + j*16 + ln)*32 + qd*8);

        #pragma unroll
        for (int i = 0; i < 4; ++i)
            #pragma unroll
            for (int j = 0; j < 4; ++j)
                acc[i][j] = __builtin_amdgcn_mfma_f32_16x16x32_bf16(af[i], bg[j], acc[i][j], 0, 0, 0);
    }

    // epilogue: C/D layout row = quad*4+reg, col = lane&15 (proven R5 form)
    #pragma unroll
    for (int i = 0; i < 4; ++i) {
        #pragma unroll
        for (int j = 0; j < 4; ++j) {
            int colg = n0 + wn + j*16 + ln;
            float bv = bias[wn + j*16 + ln];
            #pragma unroll
            for (int r = 0; r < 4; ++r) {
                int rowg = m0 + wm + i*16 + qd*4 + r;
                float v = acc[i][j][r] + bv;
                if (MODE == 0) {
                    C0[(size_t)rowg*1024 + colg] = v;
                } else if (colg < 1024) {
                    Qbf[(size_t)rowg*1024 + colg] = (bf16)(v * 0.125f);
                } else if (colg < 1280) {
                    int c2 = colg - 1024;
                    C1[(size_t)(c2 >> 6)*(SEQ*HD_) + (size_t)rowg*HD_ + (c2 & 63)] = v;
                } else {
                    int c2 = colg - 1280;
                    C2[(size_t)(c2 >> 6)*(SEQ*HD_) + (size_t)rowg*HD_ + (c2 & 63)] = v;
                }
            }
        }
    }
}

// ---------------------------------------------------------------------------
// Flash attention, causal GQA, full MFMA (byte-identical to R9/R10-proven).
// 64-row Q blocks, grid 1024 LPT-ordered; fixed-base softmax (m=16), l
// deferred to the epilogue. Q bf16 x0.125; K [4][T][64]; V^T [4][64][T].
// ---------------------------------------------------------------------------
__global__ __launch_bounds__(256)
void attn_fwd(const bf16* __restrict__ Q, const bf16* __restrict__ Kc,
              const bf16* __restrict__ VT, bf16* __restrict__ att)
{
    const int bid  = blockIdx.x;           // 0..1023
    const int head = bid & 15;
    const int mt   = 63 - (bid >> 4);      // descending work: LPT scheduling
    const int qb   = mt * 64;
    const int kvh  = head >> 2;

    const int tid = threadIdx.x, lane = tid & 63, wave = tid >> 6;
    const int qd = lane >> 4, ln = lane & 15;
    const int rw0 = qb + wave * 16;        // 16 Q rows per wave

    __shared__ bf16 Ks[64*72];             // [t][d], +8 pad (proven)
    __shared__ bf16 Vt[64*72];             // [d][t], +8 pad (proven)
    __shared__ bf16 Ps[4][16*72];          // per-wave P, +8 pad

    const bf16* Kbase = Kc + (size_t)kvh * SEQ * HD_;
    const bf16* Vbase = VT + (size_t)kvh * HD_ * SEQ;

    bf16x8 aq[2];
    #pragma unroll
    for (int ks = 0; ks < 2; ++ks)
        aq[ks] = *(const bf16x8*)(Q + (size_t)(rw0 + ln)*DIM_ + head*HD_ + ks*32 + qd*8);

    f32x4 o[4] = {};
    float l_p[4] = {0.f, 0.f, 0.f, 0.f};

    const float LOG2E = 1.4426950408889634f;
    const float C16   = 16.0f * LOG2E;
    const int nkt = mt + 1;

    for (int kt = 0; kt < nkt; ++kt) {
        const int kb = kt * 64;

        bf16x8 rk[2], rv[2];
        #pragma unroll
        for (int i = 0; i < 2; ++i) {
            int s = i*256 + tid;
            int r8 = s >> 3, ch = s & 7;
            rk[i] = *(const bf16x8*)(Kbase + (size_t)(kb + r8)*HD_ + ch*8);
            rv[i] = *(const bf16x8*)(Vbase + (size_t)r8*SEQ + kb + ch*8);
        }
        __syncthreads();
        #pragma unroll
        for (int i = 0; i < 2; ++i) {
            int s = i*256 + tid;
            int r8 = s >> 3, ch = s & 7;
            *(bf16x8*)(Ks + r8*72 + ch*8) = rk[i];
            *(bf16x8*)(Vt + r8*72 + ch*8) = rv[i];
        }
        __syncthreads();

        f32x4 S[4] = {};
        #pragma unroll
        for (int ks = 0; ks < 2; ++ks) {
            bf16x8 bk[4];
            #pragma unroll
            for (int nf = 0; nf < 4; ++nf)
                bk[nf] = *(const bf16x8*)(Ks + (nf*16 + ln)*72 + ks*32 + qd*8);
            #pragma unroll
            for (int nf = 0; nf < 4; ++nf)
                S[nf] = __builtin_amdgcn_mfma_f32_16x16x32_bf16(aq[ks], bk[nf], S[nf], 0, 0, 0);
        }

        if (kt == nkt - 1) {
            #pragma unroll
            for (int nf = 0; nf < 4; ++nf) {
                int col = kb + nf*16 + ln;
                #pragma unroll
                for (int r = 0; r < 4; ++r) {
                    int row = rw0 + qd*4 + r;
                    if (col > row) S[nf][r] = NEG_BIG;
                }
            }
        }

        bf16* Pw = &Ps[wave][0];
        #pragma unroll
        for (int r = 0; r < 4; ++r) {
            #pragma unroll
            for (int nf = 0; nf < 4; ++nf) {
                float p = exp2f(S[nf][r] * LOG2E - C16);
                l_p[r] += p;
                Pw[(qd*4 + r)*72 + nf*16 + ln] = (bf16)p;
            }
        }
        asm volatile("s_waitcnt lgkmcnt(0)" ::: "memory");

        #pragma unroll
        for (int ks = 0; ks < 2; ++ks) {
            bf16x8 bv[4];
            #pragma unroll
            for (int nf = 0; nf < 4; ++nf)
                bv[nf] = *(const bf16x8*)(Vt + (nf*16 + ln)*72 + ks*32 + qd*8);
            bf16x8 ap = *(const bf16x8*)(&Ps[wave][ln*72 + ks*32 + qd*8]);
            #pragma unroll
            for (int nf = 0; nf < 4; ++nf)
                o[nf] = __builtin_amdgcn_mfma_f32_16x16x32_bf16(ap, bv[nf], o[nf], 0, 0, 0);
        }
    }

    #pragma unroll
    for (int r = 0; r < 4; ++r) {
        float l = l_p[r];
        l += __shfl_xor(l, 1);
        l += __shfl_xor(l, 2);
        l += __shfl_xor(l, 4);
        l += __shfl_xor(l, 8);
        float inv = 1.0f / l;
        int trow = rw0 + qd*4 + r;
        #pragma unroll
        for (int nf = 0; nf < 4; ++nf)
            att[(size_t)trow*DIM_ + head*HD_ + nf*16 + ln] = (bf16)(o[nf][r] * inv);
    }
}

extern "C" void kernel_launch(void* const* d_in, const int* in_sizes, int n_in,
                              void* d_out, int out_size, void* d_ws, size_t ws_size,
                              hipStream_t stream)
{
    const float* x  = (const float*)d_in[0];
    // d_in[1] = causal mask (bool tril) -> not read
    const float* qw = (const float*)d_in[2];
    const float* qb = (const float*)d_in[3];
    const float* kw = (const float*)d_in[4];
    const float* kb = (const float*)d_in[5];
    const float* vw = (const float*)d_in[6];
    const float* vb = (const float*)d_in[7];
    const float* ow = (const float*)d_in[8];
    const float* ob = (const float*)d_in[9];

    float* out  = (float*)d_out;                       // [4096][1024] fp32 final
    float* kout = out  + (size_t)SEQ * DIM_;           // [4][4096][64] fp32 final
    float* vout = kout + (size_t)4 * SEQ * HD_;        // [4][4096][64] fp32 final

    // bf16 scratch inside the dead 16 MB out region (overwritten by O-proj):
    bf16*  q_bf  = (bf16*)d_out;                       // [4096][1024]  @ +0   (8 MB)
    bf16*  k_bf  = q_bf + (size_t)SEQ * DIM_;          // [4][4096][64] @ +8M  (2 MB)
    bf16*  vT_bf = k_bf + (size_t)4 * SEQ * HD_;       // [4][64][4096] @ +10M (2 MB)
    bf16*  wcat  = vT_bf + (size_t)4 * HD_ * SEQ;      // [1536][1024]  @ +12M (3 MB)
    float* bcat  = (float*)(wcat + (size_t)1536*1024); //               @ +15M (6 KB)
    // d_ws (8 MB): x_bf during QKV gemm, then att (stream-ordered aliasing,
    // proven R10).
    bf16* x_bf = (bf16*)d_ws;                          // [4096][1024] bf16
    bf16* att  = (bf16*)d_ws;                          // [4096][1024] bf16

    // pre-pass: bf16 conversions (x, qkv weights, biases)
    cvt_pre<<<dim3(2816), 256, 0, stream>>>(x, qw, kw, vw, qb, kb, vb,
                                            x_bf, wcat, bcat);
    // QKV projection: Q->q_bf, K->kout fp32, V->vout fp32 (R5-proven epilogue)
    gemm_bt<1><<<dim3(32, 12), 256, 0, stream>>>(x_bf, wcat, bcat,
                                                 nullptr, kout, vout, q_bf);
    // derive bf16 K and transposed V from the fp32 finals (coalesced)
    kv_cvt<<<dim3(256), 256, 0, stream>>>(kout, vout, k_bf, vT_bf);
    // causal GQA flash attention (R9/R10-proven)
    attn_fwd<<<dim3(1024), 256, 0, stream>>>(q_bf, k_bf, vT_bf, att);
    // output projection: att bf16 @ ow^T -> out fp32 (overwrites scratch)
    gemm_bt<0><<<dim3(32, 8), 256, 0, stream>>>(att, ow, ob,
                                                out, nullptr, nullptr, nullptr);
}